// Round 6
// baseline (254.231 us; speedup 1.0000x reference)
//
#include <hip/hip_runtime.h>
#include <hip/hip_cooperative_groups.h>
#include <math.h>

namespace cg = cooperative_groups;

// Problem constants (from reference)
#define BATCH 16
#define NBOX  2000
#define NCLS  81
#define NCLS1 80        // classes 1..80 participate in NMS (class 0 invalid)
#define MAXI  100
#define SURV_MAX 2048   // per-batch survivor list capacity (>= NBOX)
#define NBLK  256
#define TPB   256

// Refine with known class id — bit-exact vs numpy reference (absmax 0.0 R1-R5).
__device__ __forceinline__ void apply_refine(
    const float* __restrict__ rois, const float* __restrict__ deltas,
    size_t row, int cid, float box[4])
{
    const float4 dr = *(const float4*)(deltas + (row * NCLS + cid) * 4);
    const float4 r  = *(const float4*)(rois + row * 4);
    float dy = __fmul_rn(dr.x, 0.1f);
    float dx = __fmul_rn(dr.y, 0.1f);
    float dh = __fmul_rn(dr.z, 0.2f);
    float dw = __fmul_rn(dr.w, 0.2f);
    float h = __fsub_rn(r.z, r.x);
    float w = __fsub_rn(r.w, r.y);
    float cy = __fadd_rn(r.x, __fmul_rn(0.5f, h));
    float cx = __fadd_rn(r.y, __fmul_rn(0.5f, w));
    cy = __fadd_rn(cy, __fmul_rn(dy, h));
    cx = __fadd_rn(cx, __fmul_rn(dx, w));
    h = __fmul_rn(h, (float)exp((double)dh));   // correctly-rounded f32 exp
    w = __fmul_rn(w, (float)exp((double)dw));
    float hy = __fmul_rn(0.5f, h), hx = __fmul_rn(0.5f, w);
    box[0] = fminf(fmaxf(__fsub_rn(cy, hy), 0.f), 1.f);
    box[1] = fminf(fmaxf(__fsub_rn(cx, hx), 0.f), 1.f);
    box[2] = fminf(fmaxf(__fadd_rn(cy, hy), 0.f), 1.f);
    box[3] = fminf(fmaxf(__fadd_rn(cx, hx), 0.f), 1.f);
}

__device__ __forceinline__ unsigned long long shfl_u64(unsigned long long v, int src) {
    unsigned lo = __shfl((unsigned)v, src);
    unsigned hi = __shfl((unsigned)(v >> 32), src);
    return ((unsigned long long)hi << 32) | lo;
}

// Single fused cooperative kernel: argmax -> per-class NMS -> ranking select.
__global__ __launch_bounds__(TPB)
void detection_fused_kernel(const float* __restrict__ rois,
                            const float* __restrict__ probs,
                            const float* __restrict__ deltas,
                            float* __restrict__ wscores,       // [B*N]
                            unsigned char* __restrict__ wcid,  // [B*N], 0 if invalid
                            int* __restrict__ survcnt,         // [B]
                            unsigned int* __restrict__ surv,   // [B][SURV_MAX]: n | cid<<16
                            float* __restrict__ out)
{
    cg::grid_group grid = cg::this_grid();
    const int blk = blockIdx.x;
    const int tid = threadIdx.x;

    // Shared buffer reused across phases:
    //   phase 1: float lp[128*81]  (41472 B)
    //   phase 3: u64 keys[<=2064]  (16512 B)
    __shared__ __align__(16) char smem[128 * NCLS * 4];
    // per-wave scratch for phase 2: cand[128] + sortn[128] u16 each
    __shared__ unsigned short wavebuf[4][256];

    // ================= Phase 1: argmax + validity (blocks 0..249) =========
    if (blk == 0 && tid < BATCH) survcnt[tid] = 0;
    if (blk < 250) {
        float* lp = (float*)smem;
        const size_t base_row = (size_t)blk * 128;
        const float4* src = (const float4*)(probs + base_row * NCLS);
        float4* dst = (float4*)lp;
        for (int i = tid; i < (128 * NCLS) / 4; i += TPB)   // coalesced stage
            dst[i] = src[i];
        __syncthreads();
        if (tid < 128) {
            const float* prow = lp + tid * NCLS;  // stride 81 dwords -> conflict-free
            float best = prow[0];
            int cid = 0;
            for (int c = 1; c < NCLS; ++c) {
                float p = prow[c];
                if (p > best) { best = p; cid = c; }  // strict > == jnp.argmax
            }
            size_t row = base_row + tid;
            wscores[row] = best;
            bool valid = (cid > 0) && (best >= 0.7f);
            wcid[row] = (unsigned char)(valid ? cid : 0);
        }
    }
    __threadfence();   // device-scope: cross-XCD visibility of wscores/wcid
    grid.sync();

    // ================= Phase 2: per-(batch,class) NMS (1280 cells) ========
    {
        const int lane = tid & 63;
        const int wave = tid >> 6;
        const int w = blk * 4 + wave;              // global wave id 0..1023
        unsigned short* cand  = &wavebuf[wave][0];   // [128]
        unsigned short* sortn = &wavebuf[wave][128]; // [128]
        for (int cell = w; cell < BATCH * NCLS1; cell += 1024) {
            const int b = cell / NCLS1;
            const int cid = (cell % NCLS1) + 1;

            // Scan 2000 rows for this class (ascending-n order).
            int cnt = 0;
            for (int base = 0; base < NBOX; base += 64) {
                int n = base + lane;
                bool mine = (n < NBOX) &&
                            (wcid[(size_t)b * NBOX + n] == (unsigned char)cid);
                unsigned long long m = __ballot(mine);
                if (mine) {
                    int pos = cnt + __popcll(m & ((1ULL << lane) - 1ULL));
                    if (pos < 128) cand[pos] = (unsigned short)n;
                }
                cnt += __popcll(m);
            }
            if (cnt == 0) continue;
            if (cnt > 128) cnt = 128;   // statistically impossible (mean ~25)

            // Per-lane keys; total order: score desc, n asc (keys distinct).
            int na = (lane < cnt) ? (int)cand[lane] : -1;
            int nb = (cnt > 64 && 64 + lane < cnt) ? (int)cand[64 + lane] : -1;
            unsigned long long ka = ~0ULL, kb = ~0ULL;
            if (na >= 0) {
                unsigned u = __float_as_uint(wscores[(size_t)b * NBOX + na]) ^ 0x80000000u;
                ka = ((unsigned long long)(~u) << 32) | (unsigned)na;
            }
            if (nb >= 0) {
                unsigned u = __float_as_uint(wscores[(size_t)b * NBOX + nb]) ^ 0x80000000u;
                kb = ((unsigned long long)(~u) << 32) | (unsigned)nb;
            }
            int ra = 0, rb = 0;
            for (int t = 0; t < cnt; ++t) {
                unsigned long long kt = (t < 64) ? shfl_u64(ka, t) : shfl_u64(kb, t - 64);
                ra += (kt < ka) ? 1 : 0;
                if (cnt > 64) rb += (kt < kb) ? 1 : 0;
            }
            if (na >= 0) sortn[ra] = (unsigned short)na;
            if (nb >= 0) sortn[rb] = (unsigned short)nb;

            // Refine own sorted slots (OFFSET coords, bit-match reference IoU).
            const float off = (float)cid * 2.0f;
            int sna = (lane < cnt) ? (int)sortn[lane] : -1;
            int snb = (cnt > 64 && 64 + lane < cnt) ? (int)sortn[64 + lane] : -1;
            float ay1 = 0, ax1 = 0, ay2 = 0, ax2 = 0, aar = 0;
            float by1 = 0, bx1 = 0, by2 = 0, bx2 = 0, bar = 0;
            if (sna >= 0) {
                float box[4];
                apply_refine(rois, deltas, (size_t)b * NBOX + sna, cid, box);
                ay1 = __fadd_rn(box[0], off); ax1 = __fadd_rn(box[1], off);
                ay2 = __fadd_rn(box[2], off); ax2 = __fadd_rn(box[3], off);
                aar = __fmul_rn(__fsub_rn(ay2, ay1), __fsub_rn(ax2, ax1));
            }
            if (snb >= 0) {
                float box[4];
                apply_refine(rois, deltas, (size_t)b * NBOX + snb, cid, box);
                by1 = __fadd_rn(box[0], off); bx1 = __fadd_rn(box[1], off);
                by2 = __fadd_rn(box[2], off); bx2 = __fadd_rn(box[3], off);
                bar = __fmul_rn(__fsub_rn(by2, by1), __fsub_rn(bx2, bx1));
            }

            // Greedy NMS via masks + shuffles (zero barriers).
            unsigned long long m0 = (cnt >= 64) ? ~0ULL : ((1ULL << cnt) - 1ULL);
            int rem = cnt - 64;
            unsigned long long m1 =
                (rem <= 0) ? 0ULL : ((rem >= 64) ? ~0ULL : ((1ULL << rem) - 1ULL));
            for (int i = 0; i < cnt - 1; ++i) {
                bool alive_i = (i < 64) ? ((m0 >> i) & 1ULL) : ((m1 >> (i - 64)) & 1ULL);
                if (!alive_i) continue;   // uniform
                float iy1, ix1, iy2, ix2, ia;
                if (i < 64) {
                    iy1 = __shfl(ay1, i); ix1 = __shfl(ax1, i);
                    iy2 = __shfl(ay2, i); ix2 = __shfl(ax2, i); ia = __shfl(aar, i);
                } else {
                    int j = i - 64;
                    iy1 = __shfl(by1, j); ix1 = __shfl(bx1, j);
                    iy2 = __shfl(by2, j); ix2 = __shfl(bx2, j); ia = __shfl(bar, j);
                }
                bool supa = false;
                if (((m0 >> lane) & 1ULL) && lane > i) {
                    float ih = fmaxf(__fsub_rn(fminf(iy2, ay2), fmaxf(iy1, ay1)), 0.f);
                    float iw = fmaxf(__fsub_rn(fminf(ix2, ax2), fmaxf(ix1, ax1)), 0.f);
                    float inter = __fmul_rn(ih, iw);
                    float uni = __fsub_rn(__fadd_rn(ia, aar), inter);
                    supa = (inter / fmaxf(uni, 1e-8f)) > 0.3f;   // IEEE div
                }
                m0 &= ~__ballot(supa);
                if (m1) {
                    bool supb = false;
                    if (((m1 >> lane) & 1ULL) && (64 + lane) > i) {
                        float ih = fmaxf(__fsub_rn(fminf(iy2, by2), fmaxf(iy1, by1)), 0.f);
                        float iw = fmaxf(__fsub_rn(fminf(ix2, bx2), fmaxf(ix1, bx1)), 0.f);
                        float inter = __fmul_rn(ih, iw);
                        float uni = __fsub_rn(__fadd_rn(ia, bar), inter);
                        supb = (inter / fmaxf(uni, 1e-8f)) > 0.3f;
                    }
                    m1 &= ~__ballot(supb);
                }
            }

            // Append survivors (one atomic per cell; order irrelevant).
            bool keepa = (m0 >> lane) & 1ULL;
            bool keepb = (m1 >> lane) & 1ULL;
            int tot = __popcll(m0) + __popcll(m1);
            int basep = 0;
            if (lane == 0 && tot > 0) basep = atomicAdd(&survcnt[b], tot);
            basep = __shfl(basep, 0);
            if (keepa) {
                int pre = __popcll(m0 & ((1ULL << lane) - 1ULL));
                surv[(size_t)b * SURV_MAX + basep + pre] =
                    (unsigned)sna | ((unsigned)cid << 16);
            }
            if (keepb) {
                int pre = __popcll(m0) + __popcll(m1 & ((1ULL << lane) - 1ULL));
                surv[(size_t)b * SURV_MAX + basep + pre] =
                    (unsigned)snb | ((unsigned)cid << 16);
            }
        }
    }
    __threadfence();   // surv/survcnt visible device-wide
    grid.sync();

    // ================= Phase 3: distributed ranking-select ================
    {
        const int b = blk >> 4;      // batch
        const int sub = blk & 15;    // 0..15; subs 0..7 cover 2048 candidates
        if (sub >= 8) return;
        unsigned long long* keys = (unsigned long long*)smem;

        int K = survcnt[b]; if (K > SURV_MAX) K = SURV_MAX;
        int Kpad = (K + 15) & ~15;

        for (int t = tid; t < K; t += TPB) {
            unsigned e = surv[(size_t)b * SURV_MAX + t];
            int n = e & 0xFFFF;
            unsigned u = __float_as_uint(wscores[(size_t)b * NBOX + n]) ^ 0x80000000u;
            keys[t] = ((unsigned long long)(~u) << 32) | (unsigned)n;
        }
        for (int t = K + tid; t < Kpad; t += TPB)
            keys[t] = ~0ULL;
        __syncthreads();

        // Rows [K, 100) are all-zero in the reference; zero once (sub==0).
        if (sub == 0 && tid >= K && tid < MAXI) {
            float* o = out + ((size_t)b * MAXI + tid) * 6;
            o[0] = 0.f; o[1] = 0.f; o[2] = 0.f; o[3] = 0.f; o[4] = 0.f; o[5] = 0.f;
        }

        int p = sub * TPB + tid;
        if (p < K) {
            const unsigned long long own = keys[p];
            const ulonglong2* k2 = (const ulonglong2*)keys;   // ds_read_b128
            int rank = 0;
            int K2 = Kpad >> 1;
#pragma unroll 8
            for (int t = 0; t < K2; ++t) {
                ulonglong2 kk = k2[t];
                rank += (kk.x < own) ? 1 : 0;
                rank += (kk.y < own) ? 1 : 0;
            }
            if (rank < MAXI) {       // rank == exact output row (keys distinct)
                unsigned e = surv[(size_t)b * SURV_MAX + p];
                int n = e & 0xFFFF;
                int cid = (int)(e >> 16);
                size_t row = (size_t)b * NBOX + n;
                float box[4];
                apply_refine(rois, deltas, row, cid, box);
                float* o = out + ((size_t)b * MAXI + rank) * 6;
                o[0] = box[0]; o[1] = box[1]; o[2] = box[2]; o[3] = box[3];
                o[4] = (float)cid; o[5] = wscores[row];
            }
        }
    }
}

extern "C" void kernel_launch(void* const* d_in, const int* in_sizes, int n_in,
                              void* d_out, int out_size, void* d_ws, size_t ws_size,
                              hipStream_t stream)
{
    const float* rois   = (const float*)d_in[0];  // (B, N, 4)
    const float* probs  = (const float*)d_in[1];  // (B, N, C)
    const float* deltas = (const float*)d_in[2];  // (B, N, C, 4)
    float* out = (float*)d_out;                   // (B, 100, 6)

    // Workspace layout (284 KB):
    //   [0,64)           survcnt i32 [16]
    //   [64,128064)      wscores f32 [32000]
    //   [128064,160064)  wcid    u8  [32000]
    //   [160064,291136)  surv    u32 [16][SURV_MAX]
    char* ws = (char*)d_ws;
    int*           survcnt = (int*)(ws);
    float*         wscores = (float*)(ws + 64);
    unsigned char* wcid    = (unsigned char*)(ws + 128064);
    unsigned int*  surv    = (unsigned int*)(ws + 160064);

    void* args[] = { (void*)&rois, (void*)&probs, (void*)&deltas,
                     (void*)&wscores, (void*)&wcid,
                     (void*)&survcnt, (void*)&surv, (void*)&out };
    hipLaunchCooperativeKernel((const void*)detection_fused_kernel,
                               dim3(NBLK), dim3(TPB), args, 0, stream);
}

// Round 7
// 141.398 us; speedup vs baseline: 1.7980x; 1.7980x over previous
//
#include <hip/hip_runtime.h>
#include <math.h>

// Problem constants (from reference)
#define BATCH 16
#define NBOX  2000
#define NCLS  81
#define NCLS1 80        // classes 1..80 participate in NMS (class 0 invalid)
#define MAXI  100
#define ROWS_PB 128     // rows per block in phase 1
#define SURV_MAX 2048   // per-batch survivor list capacity (>= NBOX)

// Refine with known class id — bit-exact vs numpy reference (absmax 0.0 R1-R6).
__device__ __forceinline__ void apply_refine(
    const float* __restrict__ rois, const float* __restrict__ deltas,
    size_t row, int cid, float box[4])
{
    const float4 dr = *(const float4*)(deltas + (row * NCLS + cid) * 4);
    const float4 r  = *(const float4*)(rois + row * 4);
    float dy = __fmul_rn(dr.x, 0.1f);
    float dx = __fmul_rn(dr.y, 0.1f);
    float dh = __fmul_rn(dr.z, 0.2f);
    float dw = __fmul_rn(dr.w, 0.2f);
    float h = __fsub_rn(r.z, r.x);
    float w = __fsub_rn(r.w, r.y);
    float cy = __fadd_rn(r.x, __fmul_rn(0.5f, h));
    float cx = __fadd_rn(r.y, __fmul_rn(0.5f, w));
    cy = __fadd_rn(cy, __fmul_rn(dy, h));
    cx = __fadd_rn(cx, __fmul_rn(dx, w));
    h = __fmul_rn(h, (float)exp((double)dh));   // correctly-rounded f32 exp
    w = __fmul_rn(w, (float)exp((double)dw));
    float hy = __fmul_rn(0.5f, h), hx = __fmul_rn(0.5f, w);
    box[0] = fminf(fmaxf(__fsub_rn(cy, hy), 0.f), 1.f);
    box[1] = fminf(fmaxf(__fsub_rn(cx, hx), 0.f), 1.f);
    box[2] = fminf(fmaxf(__fadd_rn(cy, hy), 0.f), 1.f);
    box[3] = fminf(fmaxf(__fadd_rn(cx, hx), 0.f), 1.f);
}

__device__ __forceinline__ unsigned long long shfl_u64(unsigned long long v, int src) {
    unsigned lo = __shfl((unsigned)v, src);
    unsigned hi = __shfl((unsigned)(v >> 32), src);
    return ((unsigned long long)hi << 32) | lo;
}

// ---- Phase 1: LDS-staged argmax (4-way ILP chains); score + valid-cid per row ----
__global__ __launch_bounds__(ROWS_PB)
void refine_argmax_kernel(const float* __restrict__ probs,
                          float* __restrict__ wscores,        // [B*N]
                          unsigned char* __restrict__ wcid,   // [B*N], 0 if invalid
                          int* __restrict__ survcnt)          // [B] (zeroed here)
{
    __shared__ __align__(16) float lp[ROWS_PB * NCLS];   // 41472 B
    const int tid = threadIdx.x;
    const size_t base_row = (size_t)blockIdx.x * ROWS_PB;
    const float4* src = (const float4*)(probs + base_row * NCLS);
    float4* dst = (float4*)lp;
    for (int i = tid; i < (ROWS_PB * NCLS) / 4; i += ROWS_PB)   // coalesced stage
        dst[i] = src[i];
    if (blockIdx.x == 0 && tid < BATCH) survcnt[tid] = 0;   // ordered by kernel boundary
    __syncthreads();
    const float* prow = lp + tid * NCLS;   // stride 81 dwords (odd) -> conflict-free
    // 4 independent max chains (ILP), then first-max-exact merge.
    float b0 = prow[0], b1 = prow[1], b2 = prow[2], b3 = prow[3];
    int   c0 = 0,       c1 = 1,       c2 = 2,       c3 = 3;
    for (int c = 4; c + 3 < NCLS; c += 4) {   // c = 4..76, covers classes 4..79
        float p0 = prow[c],     p1 = prow[c + 1];
        float p2 = prow[c + 2], p3 = prow[c + 3];
        if (p0 > b0) { b0 = p0; c0 = c; }       // strict > keeps earliest in chain
        if (p1 > b1) { b1 = p1; c1 = c + 1; }
        if (p2 > b2) { b2 = p2; c2 = c + 2; }
        if (p3 > b3) { b3 = p3; c3 = c + 3; }
    }
    { float p = prow[80]; if (p > b0) { b0 = p; c0 = 80; } }   // remainder
    // Merge: on equal values prefer lower class index == jnp.argmax first-max.
    if (b1 > b0 || (b1 == b0 && c1 < c0)) { b0 = b1; c0 = c1; }
    if (b3 > b2 || (b3 == b2 && c3 < c2)) { b2 = b3; c2 = c3; }
    if (b2 > b0 || (b2 == b0 && c2 < c0)) { b0 = b2; c0 = c2; }
    size_t row = base_row + tid;
    wscores[row] = b0;
    bool valid = (c0 > 0) && (b0 >= 0.7f);
    wcid[row] = (unsigned char)(valid ? c0 : 0);
}

// ---- Phase 2: register-batched scan + shuffle rank-sort + shuffle NMS ----
__global__ __launch_bounds__(64)
void classnms_kernel(const float* __restrict__ rois,
                     const float* __restrict__ deltas,
                     const float* __restrict__ wscores,
                     const unsigned char* __restrict__ wcid,
                     int* __restrict__ survcnt,                // [B]
                     unsigned int* __restrict__ surv)          // [B][SURV_MAX]: n | cid<<16
{
    const int c = blockIdx.x;            // 0..79 -> cid = c+1
    const int b = blockIdx.y;
    const int cid = c + 1;
    const int lane = threadIdx.x;
    __shared__ unsigned short cand[128];
    __shared__ unsigned short sortn[128];

    // Preload batch's 2000 wcid bytes: exactly 125 uint4; ONE memory round-trip.
    const uint4* wv = (const uint4*)(wcid + (size_t)b * NBOX);   // 2000 = 16*125, aligned
    uint4 v0 = wv[lane];                                         // bytes [lane*16, +16)
    uint4 v1 = make_uint4(0u, 0u, 0u, 0u);                       // byte 0 != cid (cid>=1)
    if (64 + lane < 125) v1 = wv[64 + lane];                     // bytes [1024+lane*16, +16)

    // 32 ballot rounds over register bytes. cand[] order is scrambled (k-major)
    // but the rank-sort below makes final order independent of cand order.
    int cnt = 0;
    unsigned wds[8] = { v0.x, v0.y, v0.z, v0.w, v1.x, v1.y, v1.z, v1.w };
#pragma unroll
    for (int wq = 0; wq < 8; ++wq) {
#pragma unroll
        for (int k = 0; k < 4; ++k) {
            bool mine = (((wds[wq] >> (8 * k)) & 0xFFu) == (unsigned)cid);
            unsigned long long m = __ballot(mine);
            if (mine) {
                int pos = cnt + __popcll(m & ((1ULL << lane) - 1ULL));
                int n = ((wq >> 2) << 10) + lane * 16 + ((wq & 3) << 2) + k;
                if (pos < 128) cand[pos] = (unsigned short)n;
            }
            cnt += __popcll(m);
        }
    }
    if (cnt == 0) return;
    if (cnt > 128) cnt = 128;   // statistically impossible (mean ~25)

    // Per-lane keys; total order: score desc, n asc (keys distinct).
    int na = (lane < cnt) ? (int)cand[lane] : -1;
    int nb = (cnt > 64 && 64 + lane < cnt) ? (int)cand[64 + lane] : -1;
    unsigned long long ka = ~0ULL, kb = ~0ULL;
    if (na >= 0) {
        unsigned u = __float_as_uint(wscores[(size_t)b * NBOX + na]) ^ 0x80000000u;
        ka = ((unsigned long long)(~u) << 32) | (unsigned)na;
    }
    if (nb >= 0) {
        unsigned u = __float_as_uint(wscores[(size_t)b * NBOX + nb]) ^ 0x80000000u;
        kb = ((unsigned long long)(~u) << 32) | (unsigned)nb;
    }
    int ra = 0, rb = 0;
    for (int t = 0; t < cnt; ++t) {
        unsigned long long kt = (t < 64) ? shfl_u64(ka, t) : shfl_u64(kb, t - 64);
        ra += (kt < ka) ? 1 : 0;
        if (cnt > 64) rb += (kt < kb) ? 1 : 0;
    }
    if (na >= 0) sortn[ra] = (unsigned short)na;
    if (nb >= 0) sortn[rb] = (unsigned short)nb;
    __syncthreads();

    // Refine own sorted slots (OFFSET coords, bit-match reference IoU).
    const float off = (float)cid * 2.0f;
    int sna = (lane < cnt) ? (int)sortn[lane] : -1;
    int snb = (cnt > 64 && 64 + lane < cnt) ? (int)sortn[64 + lane] : -1;
    float ay1 = 0, ax1 = 0, ay2 = 0, ax2 = 0, aar = 0;
    float by1 = 0, bx1 = 0, by2 = 0, bx2 = 0, bar = 0;
    if (sna >= 0) {
        float box[4];
        apply_refine(rois, deltas, (size_t)b * NBOX + sna, cid, box);
        ay1 = __fadd_rn(box[0], off); ax1 = __fadd_rn(box[1], off);
        ay2 = __fadd_rn(box[2], off); ax2 = __fadd_rn(box[3], off);
        aar = __fmul_rn(__fsub_rn(ay2, ay1), __fsub_rn(ax2, ax1));
    }
    if (snb >= 0) {
        float box[4];
        apply_refine(rois, deltas, (size_t)b * NBOX + snb, cid, box);
        by1 = __fadd_rn(box[0], off); bx1 = __fadd_rn(box[1], off);
        by2 = __fadd_rn(box[2], off); bx2 = __fadd_rn(box[3], off);
        bar = __fmul_rn(__fsub_rn(by2, by1), __fsub_rn(bx2, bx1));
    }

    // Greedy NMS via masks + shuffles (zero barriers, zero LDS).
    unsigned long long m0 = (cnt >= 64) ? ~0ULL : ((1ULL << cnt) - 1ULL);
    int rem = cnt - 64;
    unsigned long long m1 = (rem <= 0) ? 0ULL : ((rem >= 64) ? ~0ULL : ((1ULL << rem) - 1ULL));
    for (int i = 0; i < cnt - 1; ++i) {
        bool alive_i = (i < 64) ? ((m0 >> i) & 1ULL) : ((m1 >> (i - 64)) & 1ULL);
        if (!alive_i) continue;   // uniform
        float iy1, ix1, iy2, ix2, ia;
        if (i < 64) {
            iy1 = __shfl(ay1, i); ix1 = __shfl(ax1, i);
            iy2 = __shfl(ay2, i); ix2 = __shfl(ax2, i); ia = __shfl(aar, i);
        } else {
            int j = i - 64;
            iy1 = __shfl(by1, j); ix1 = __shfl(bx1, j);
            iy2 = __shfl(by2, j); ix2 = __shfl(bx2, j); ia = __shfl(bar, j);
        }
        bool supa = false;
        if (((m0 >> lane) & 1ULL) && lane > i) {
            float ih = fmaxf(__fsub_rn(fminf(iy2, ay2), fmaxf(iy1, ay1)), 0.f);
            float iw = fmaxf(__fsub_rn(fminf(ix2, ax2), fmaxf(ix1, ax1)), 0.f);
            float inter = __fmul_rn(ih, iw);
            float uni = __fsub_rn(__fadd_rn(ia, aar), inter);
            supa = (inter / fmaxf(uni, 1e-8f)) > 0.3f;   // IEEE div, matches ref
        }
        m0 &= ~__ballot(supa);
        if (m1) {
            bool supb = false;
            if (((m1 >> lane) & 1ULL) && (64 + lane) > i) {
                float ih = fmaxf(__fsub_rn(fminf(iy2, by2), fmaxf(iy1, by1)), 0.f);
                float iw = fmaxf(__fsub_rn(fminf(ix2, bx2), fmaxf(ix1, bx1)), 0.f);
                float inter = __fmul_rn(ih, iw);
                float uni = __fsub_rn(__fadd_rn(ia, bar), inter);
                supb = (inter / fmaxf(uni, 1e-8f)) > 0.3f;
            }
            m1 &= ~__ballot(supb);
        }
    }

    // Append survivors: one atomic per block (order irrelevant, rank-selected later).
    bool keepa = (m0 >> lane) & 1ULL;
    bool keepb = (m1 >> lane) & 1ULL;
    int tot = __popcll(m0) + __popcll(m1);
    int basep = 0;
    if (lane == 0 && tot > 0) basep = atomicAdd(&survcnt[b], tot);
    basep = __shfl(basep, 0);
    if (keepa) {
        int pre = __popcll(m0 & ((1ULL << lane) - 1ULL));
        surv[(size_t)b * SURV_MAX + basep + pre] = (unsigned)sna | ((unsigned)cid << 16);
    }
    if (keepb) {
        int pre = __popcll(m0) + __popcll(m1 & ((1ULL << lane) - 1ULL));
        surv[(size_t)b * SURV_MAX + basep + pre] = (unsigned)snb | ((unsigned)cid << 16);
    }
}

// ---- Phase 3: distributed ranking-select, b128 LDS reads, 128-thread blocks ----
// Grid (16, B): block g owns candidates [g*128, g*128+128).
__global__ __launch_bounds__(128)
void select_kernel(const float* __restrict__ rois,
                   const float* __restrict__ deltas,
                   const float* __restrict__ wscores,
                   const int* __restrict__ survcnt,
                   const unsigned int* __restrict__ surv,
                   float* __restrict__ out)
{
    const int g = blockIdx.x;      // 0..15
    const int b = blockIdx.y;
    const int tid = threadIdx.x;
    __shared__ __align__(16) unsigned long long keys[SURV_MAX + 16];

    int K = survcnt[b]; if (K > SURV_MAX) K = SURV_MAX;
    int Kpad = (K + 15) & ~15;

    for (int t = tid; t < K; t += 128) {
        unsigned e = surv[(size_t)b * SURV_MAX + t];
        int n = e & 0xFFFF;
        unsigned u = __float_as_uint(wscores[(size_t)b * NBOX + n]) ^ 0x80000000u;
        keys[t] = ((unsigned long long)(~u) << 32) | (unsigned)n;
    }
    for (int t = K + tid; t < Kpad; t += 128)
        keys[t] = ~0ULL;           // pad: never counts as smaller
    __syncthreads();

    // Rows [K, 100) are all-zero in the reference; zero them once (block g=0).
    if (g == 0 && tid >= K && tid < MAXI) {
        float* o = out + ((size_t)b * MAXI + tid) * 6;
        o[0] = 0.f; o[1] = 0.f; o[2] = 0.f; o[3] = 0.f; o[4] = 0.f; o[5] = 0.f;
    }

    int p = g * 128 + tid;
    if (p < K) {
        const unsigned long long own = keys[p];
        const ulonglong2* k2 = (const ulonglong2*)keys;   // ds_read_b128 broadcasts
        int rank = 0;
        int K2 = Kpad >> 1;
#pragma unroll 8
        for (int t = 0; t < K2; ++t) {
            ulonglong2 kk = k2[t];
            rank += (kk.x < own) ? 1 : 0;
            rank += (kk.y < own) ? 1 : 0;
        }
        if (rank < MAXI) {         // rank == exact output row (keys distinct, dense)
            unsigned e = surv[(size_t)b * SURV_MAX + p];
            int n = e & 0xFFFF;
            int cid = (int)(e >> 16);
            size_t row = (size_t)b * NBOX + n;
            float box[4];
            apply_refine(rois, deltas, row, cid, box);
            float* o = out + ((size_t)b * MAXI + rank) * 6;
            o[0] = box[0]; o[1] = box[1]; o[2] = box[2]; o[3] = box[3];
            o[4] = (float)cid; o[5] = wscores[row];
        }
    }
}

extern "C" void kernel_launch(void* const* d_in, const int* in_sizes, int n_in,
                              void* d_out, int out_size, void* d_ws, size_t ws_size,
                              hipStream_t stream)
{
    const float* rois   = (const float*)d_in[0];  // (B, N, 4)
    const float* probs  = (const float*)d_in[1];  // (B, N, C)
    const float* deltas = (const float*)d_in[2];  // (B, N, C, 4)
    float* out = (float*)d_out;                   // (B, 100, 6)

    // Workspace layout (284 KB), all 16B-aligned:
    //   [0,64)           survcnt i32 [16]
    //   [64,128064)      wscores f32 [32000]
    //   [128064,160064)  wcid    u8  [32000]
    //   [160064,291136)  surv    u32 [16][SURV_MAX]
    char* ws = (char*)d_ws;
    int*           survcnt = (int*)(ws);
    float*         wscores = (float*)(ws + 64);
    unsigned char* wcid    = (unsigned char*)(ws + 128064);
    unsigned int*  surv    = (unsigned int*)(ws + 160064);

    refine_argmax_kernel<<<dim3((BATCH * NBOX) / ROWS_PB), dim3(ROWS_PB), 0, stream>>>(
        probs, wscores, wcid, survcnt);
    classnms_kernel<<<dim3(NCLS1, BATCH), dim3(64), 0, stream>>>(
        rois, deltas, wscores, wcid, survcnt, surv);
    select_kernel<<<dim3(16, BATCH), dim3(128), 0, stream>>>(
        rois, deltas, wscores, survcnt, surv, out);
}